// Round 9
// baseline (340.394 us; speedup 1.0000x reference)
//
#include <hip/hip_runtime.h>
#include <hip/hip_fp16.h>

// RaBitQ forward, fused: quantize + in-kernel MFMA dequantize.
// x: 262144 vectors of D=128 fp32. P: 128x128 fp32 orthonormal.
// out f32 concat: x_hat[262144*128] | packed[262144*16] | norms16[262144] | x016[262144]
//
// prep_bfrags: writes 32 KiB of MFMA-ready bf16 B-frags (kernel-B prologue math,
//   proven R5/R8) into d_ws. L1-resident for the fused kernel.
// rabitq_fused: R8 quantize VERBATIM per 8-vec pass (LDS fp32 P swizzled,
//   reg-staged x -> wave slot, ascending-d fmaf chain -> signs bit-identical),
//   with (a) DPP-based s1/n2 reduce (only feeds fp16-rounded outputs, 2% thr),
//   (b) per-16-vec-group dequant fused in: masks/scales from wave-uniform
//   ballots via sel16 trees (R2-proven), B-frags from d_ws, 32 MFMAs, stores.
// LDS = 64K P + 16 waves x 4K x-slots = 131072 (proven launchable R7/R8).

#define NVEC_TOTAL (4 * 16 * 4096)

typedef short short8 __attribute__((ext_vector_type(8)));
typedef float f32x4 __attribute__((ext_vector_type(4)));
typedef unsigned int u32x4v __attribute__((ext_vector_type(4)));
typedef unsigned long long ull;

__device__ __forceinline__ float rfl_f(float v) {
  return __int_as_float(__builtin_amdgcn_readfirstlane(__float_as_int(v)));
}

__device__ __forceinline__ ull sel8_u64(const ull* a, int s) {
  ull r0 = (s & 1) ? a[1] : a[0];
  ull r1 = (s & 1) ? a[3] : a[2];
  ull r2 = (s & 1) ? a[5] : a[4];
  ull r3 = (s & 1) ? a[7] : a[6];
  ull r4 = (s & 2) ? r1 : r0;
  ull r5 = (s & 2) ? r3 : r2;
  return (s & 4) ? r5 : r4;
}

__device__ __forceinline__ float sel8_f(const float* a, int s) {
  float r0 = (s & 1) ? a[1] : a[0];
  float r1 = (s & 1) ? a[3] : a[2];
  float r2 = (s & 1) ? a[5] : a[4];
  float r3 = (s & 1) ? a[7] : a[6];
  float r4 = (s & 2) ? r1 : r0;
  float r5 = (s & 2) ? r3 : r2;
  return (s & 4) ? r5 : r4;
}

__device__ __forceinline__ ull sel16_u64(const ull* a, int s) {
  ull lo = sel8_u64(a, s);
  ull hi = sel8_u64(a + 8, s);
  return (s & 8) ? hi : lo;
}

__device__ __forceinline__ float sel16_f(const float* a, int s) {
  float lo = sel8_f(a, s);
  float hi = sel8_f(a + 8, s);
  return (s & 8) ? hi : lo;
}

template <int CTRL>
__device__ __forceinline__ float dpp_add(float v) {
  int t = __builtin_amdgcn_update_dpp(0, __float_as_int(v), CTRL, 0xF, 0xF, true);
  return v + __int_as_float(t);
}

// full 64-lane sum: row_ror 1,2,4,8 (VALU pipe) + xor16 (ds_swizzle) + xor32 (shfl)
__device__ __forceinline__ float wave_sum(float v) {
  v = dpp_add<0x121>(v);
  v = dpp_add<0x122>(v);
  v = dpp_add<0x124>(v);
  v = dpp_add<0x128>(v);
  v += __int_as_float(__builtin_amdgcn_ds_swizzle(__float_as_int(v), 0x401F));
  v += __shfl_xor(v, 32);
  return v;
}

__device__ __forceinline__ unsigned short f2bf(float f) {  // fp32 -> bf16 RNE
  unsigned u = __float_as_uint(f);
  return (unsigned short)((u + 0x7FFFu + ((u >> 16) & 1u)) >> 16);
}

// ============ prep: build bf16 B-frags (MFMA layout) into d_ws ============
__global__ __launch_bounds__(256, 4) void prep_bfrags(const float* __restrict__ Pm,
                                                      unsigned* __restrict__ ws) {
  const int tid = threadIdx.x;
#pragma unroll
  for (int i = 0; i < 8; ++i) {
    const int s = tid + i * 256;
    const int ks = s >> 9, n = (s >> 6) & 7, l = s & 63;
    const int kb = ks * 32 + (l >> 4) * 8;
    const int f = n * 16 + (l & 15);
    u32x4v wv;
#pragma unroll
    for (int u = 0; u < 4; ++u) {
      const float p0 = Pm[(size_t)(kb + 2 * u) * 128 + f];
      const float p1 = Pm[(size_t)(kb + 2 * u + 1) * 128 + f];
      wv[u] = (unsigned)f2bf(p0) | ((unsigned)f2bf(p1) << 16);
    }
    *(u32x4v*)(ws + s * 4) = wv;
  }
}

// ========================= fused quantize + dequantize =========================
__global__ __launch_bounds__(1024, 4) void rabitq_fused(const float* __restrict__ x,
                                                        const float* __restrict__ Pm,
                                                        const unsigned* __restrict__ bw,
                                                        float* __restrict__ out) {
  extern __shared__ __align__(16) char smem[];
  float* const Pl = (float*)smem;     // 64 KiB swizzled fp32 P
  char* const xs = smem + 65536;      // 16 wave-slots x 4 KiB

  const int tid = threadIdx.x;
  const int lane = tid & 63;
  const int ww = tid >> 6;
  const int l15 = lane & 15, lg = lane >> 4;

  // ---- stage P into LDS, swizzled (16B blocks, j ^ (row&7)) : R8 verbatim ----
  {
    const int r = tid >> 3;
    const int q = tid & 7;
#pragma unroll
    for (int c = 0; c < 4; ++c) {
      const int dd = q * 16 + c * 4;
      const int sj = (((dd >> 2) ^ (r & 7)) << 2);
      const float4 v = *(const float4*)(Pm + (size_t)r * 128 + dd);
      *(float4*)(&Pl[r * 128 + sj]) = v;
    }
  }
  __syncthreads();

  const int w = blockIdx.x * 16 + ww;  // global wave id
  float* const out_pack = out + (size_t)NVEC_TOTAL * 128;
  float* const out_norm = out_pack + (size_t)NVEC_TOTAL * 16;
  float* const out_x0   = out_norm + NVEC_TOTAL;

  const int sw1 = lane & 7;
  float* const xb = (float*)(xs + ww * 4096);
  const int lsub = (lane >> 5);
  const int lcol = (lane & 31) * 4;

  // ---- prologue: prefetch pass-0 x (per-lane, coalesced) : R8 verbatim ----
  float4 pf0, pf1, pf2, pf3;
  {
    const int vb = w * 32;
    pf0 = *(const float4*)(x + (size_t)(vb + 0 + lsub) * 128 + lcol);
    pf1 = *(const float4*)(x + (size_t)(vb + 2 + lsub) * 128 + lcol);
    pf2 = *(const float4*)(x + (size_t)(vb + 4 + lsub) * 128 + lcol);
    pf3 = *(const float4*)(x + (size_t)(vb + 6 + lsub) * 128 + lcol);
  }

#pragma unroll
  for (int g = 0; g < 2; ++g) {
    ull gL[16], gH[16];   // per-vec 64-bit sign masks (wave-uniform)
    float gSc[16];        // per-vec n16*x016 (wave-uniform)

#pragma unroll
    for (int p = 0; p < 2; ++p) {
      const int t = g * 2 + p;
      const int vbase = w * 32 + t * 8;

      // ---- write staged regs to wave slot : R8 verbatim ----
      {
        char* const dst = (char*)xb + lane * 16;
        *(float4*)(dst + 0)    = pf0;
        *(float4*)(dst + 1024) = pf1;
        *(float4*)(dst + 2048) = pf2;
        *(float4*)(dst + 3072) = pf3;
      }

      // ---- prefetch next pass ----
      if (t + 1 < 4) {
        const int vb = w * 32 + (t + 1) * 8;
        pf0 = *(const float4*)(x + (size_t)(vb + 0 + lsub) * 128 + lcol);
        pf1 = *(const float4*)(x + (size_t)(vb + 2 + lsub) * 128 + lcol);
        pf2 = *(const float4*)(x + (size_t)(vb + 4 + lsub) * 128 + lcol);
        pf3 = *(const float4*)(x + (size_t)(vb + 6 + lsub) * 128 + lcol);
      }

      // ---- x_rot = x @ P^T : R8-verbatim chain (signs proven) ----
      float acc_lo[8], acc_hi[8];
#pragma unroll
      for (int v = 0; v < 8; ++v) { acc_lo[v] = 0.f; acc_hi[v] = 0.f; }

#pragma unroll 2
      for (int j = 0; j < 32; ++j) {
        const int js = ((j ^ sw1) << 2);
        const float4 pl = *(const float4*)(&Pl[lane * 128 + js]);
        const float4 ph = *(const float4*)(&Pl[(lane + 64) * 128 + js]);
#pragma unroll
        for (int v = 0; v < 8; ++v) {
          const float4 xv = *(const float4*)(xb + v * 128 + j * 4);
          float al = acc_lo[v], ah = acc_hi[v];
          al = fmaf(xv.x, pl.x, al); ah = fmaf(xv.x, ph.x, ah);
          al = fmaf(xv.y, pl.y, al); ah = fmaf(xv.y, ph.y, ah);
          al = fmaf(xv.z, pl.z, al); ah = fmaf(xv.z, ph.z, ah);
          al = fmaf(xv.w, pl.w, al); ah = fmaf(xv.w, ph.w, ah);
          acc_lo[v] = al; acc_hi[v] = ah;
        }
      }

      // ---- signs (verbatim), norm/x0 with DPP reduce ----
      ull abl[8], abh[8];
      float n16v[8], x0v[8];
#pragma unroll
      for (int v = 0; v < 8; ++v) {
        abl[v] = __ballot(acc_lo[v] >= 0.0f);
        abh[v] = __ballot(acc_hi[v] >= 0.0f);
        const float a1 = fabsf(acc_lo[v]);
        const float a2 = fabsf(acc_hi[v]);
        const float s1 = wave_sum(a1 + a2);
        const float n2 = wave_sum(fmaf(a1, a1, a2 * a2));
        const float norm = fmaxf(sqrtf(n2), 1e-8f);
        const float n16  = __half2float(__float2half(norm));
        const float x0   = s1 / (128.0f * norm);
        const float x016 = __half2float(__float2half(x0));
        n16v[v] = rfl_f(n16);
        x0v[v]  = rfl_f(x016);
        gL[p * 8 + v] = abl[v];
        gH[p * 8 + v] = abh[v];
        gSc[p * 8 + v] = rfl_f(n16 * x016);
      }

      // ---- packed bytes / norms16 / x016 stores : R8 verbatim ----
      {
        const int s = lane & 7;
        const int jb = lane >> 3;
        const ull el = sel8_u64(abl, s);
        const ull eh = sel8_u64(abh, s);
        const float fl = (float)((unsigned)(el >> (8 * jb)) & 255u);
        const float fh = (float)((unsigned)(eh >> (8 * jb)) & 255u);
        out_pack[(size_t)(vbase + s) * 16 + jb] = fl;
        out_pack[(size_t)(vbase + s) * 16 + 8 + jb] = fh;
        if (lane < 16) {
          const float nsel = sel8_f(n16v, s);
          const float xsel = sel8_f(x0v, s);
          if (lane < 8) out_norm[vbase + s] = nsel;
          else          out_x0[vbase + s] = xsel;
        }
      }
    }

    // ================= dequant group g: vecs gvb..gvb+15 =================
    const int gvb = w * 32 + g * 16;

    // lane's vec = gvb + l15: mask words from wave-uniform ballots (sel16 tree)
    const ull selL = sel16_u64(gL, l15);
    const ull selH = sel16_u64(gH, l15);
    unsigned mw[4];
    mw[0] = (unsigned)selL; mw[1] = (unsigned)(selL >> 32);
    mw[2] = (unsigned)selH; mw[3] = (unsigned)(selH >> 32);

    // A-frags : R2/R5-proven construction
    short8 a8[4];
#pragma unroll
    for (int ks = 0; ks < 4; ++ks) {
      const unsigned nb = (~mw[ks]) >> (lg * 8);
      u32x4v ta;
      ta[0] = 0x3F803F80u | ((nb & 1u) << 15)        | ((nb & 2u) << 30);
      ta[1] = 0x3F803F80u | (((nb >> 2) & 1u) << 15) | (((nb >> 2) & 2u) << 30);
      ta[2] = 0x3F803F80u | (((nb >> 4) & 1u) << 15) | (((nb >> 4) & 2u) << 30);
      ta[3] = 0x3F803F80u | (((nb >> 6) & 1u) << 15) | (((nb >> 6) & 2u) << 30);
      a8[ks] = __builtin_bit_cast(short8, ta);
    }

    // D = S @ bf16(P), B-frags from d_ws (L1-hot 32 KiB)
    f32x4 dacc[8];
#pragma unroll
    for (int n = 0; n < 8; ++n) { dacc[n][0] = 0.f; dacc[n][1] = 0.f; dacc[n][2] = 0.f; dacc[n][3] = 0.f; }
#pragma unroll
    for (int n = 0; n < 8; ++n) {
#pragma unroll
      for (int ks = 0; ks < 4; ++ks) {
        const short8 b8 = __builtin_bit_cast(short8, *(const u32x4v*)(bw + (size_t)(ks * 512 + n * 64 + lane) * 4));
        dacc[n] = __builtin_amdgcn_mfma_f32_16x16x32_bf16(a8[ks], b8, dacc[n], 0, 0, 0);
      }
    }

    // scales + stores (C/D: col=l15, row=lg*4+reg — proven)
    float sc[4];
#pragma unroll
    for (int r = 0; r < 4; ++r) sc[r] = sel16_f(gSc, lg * 4 + r);
#pragma unroll
    for (int r = 0; r < 4; ++r) {
      float* op = out + (size_t)(gvb + lg * 4 + r) * 128 + l15;
#pragma unroll
      for (int n = 0; n < 8; ++n) op[n * 16] = sc[r] * dacc[n][r];
    }
  }
}

extern "C" void kernel_launch(void* const* d_in, const int* in_sizes, int n_in,
                              void* d_out, int out_size, void* d_ws, size_t ws_size,
                              hipStream_t stream) {
  const float* x  = (const float*)d_in[0];
  const float* Pm = (const float*)d_in[1];
  float* out = (float*)d_out;
  // prep: 2048 B-frag slots x 16B = 32 KiB into d_ws.
  hipLaunchKernelGGL(prep_bfrags, dim3(1), dim3(256), 0, stream, Pm, (unsigned*)d_ws);
  // fused: 262144 vec / (16 waves * 32 vec) = 512 blocks; LDS 128 KiB (proven).
  hipLaunchKernelGGL(rabitq_fused, dim3(512), dim3(1024), 131072, stream,
                     x, Pm, (const unsigned*)d_ws, out);
}

// Round 10
// 263.441 us; speedup vs baseline: 1.2921x; 1.2921x over previous
//
#include <hip/hip_runtime.h>
#include <hip/hip_fp16.h>

// RaBitQ forward, fused single kernel: quantize + in-kernel MFMA dequantize.
// x: 262144 vectors of D=128 fp32. P: 128x128 fp32 orthonormal.
// out f32 concat: x_hat[262144*128] | packed[262144*16] | norms16[262144] | x016[262144]
//
// R9 structure with ONE fix: B-frags live in LDS (built per block from global
// Pm with the R5-proven loop), not in a global d_ws buffer that L2 kept
// evicting (R9: +270MB HBM re-fetch on the dequant critical path).
// LDS = 64K fp32 P (swizzled) + 16 x 4K wave x-slots + 32K bf16 B-frags
//     = 163840 B (full 160 KiB/CU; HK/AITER precedent, 128K proven R7/R8).
// Quantize per 8-vec pass: R8 VERBATIM (reg-staged x -> wave slot, LDS P rows,
//   ascending-d fmaf chain -> signs bit-identical to proven R1/R5/R8).
// Dequant per 16-vec group: R9 path (sel16 masks/scales from uniform ballots,
//   R2/R5-proven A-frag build + MFMA + C/D layout), B from LDS (R5-proven).

#define NVEC_TOTAL (4 * 16 * 4096)

typedef short short8 __attribute__((ext_vector_type(8)));
typedef float f32x4 __attribute__((ext_vector_type(4)));
typedef unsigned int u32x4v __attribute__((ext_vector_type(4)));
typedef unsigned long long ull;

__device__ __forceinline__ float rfl_f(float v) {
  return __int_as_float(__builtin_amdgcn_readfirstlane(__float_as_int(v)));
}

__device__ __forceinline__ ull sel8_u64(const ull* a, int s) {
  ull r0 = (s & 1) ? a[1] : a[0];
  ull r1 = (s & 1) ? a[3] : a[2];
  ull r2 = (s & 1) ? a[5] : a[4];
  ull r3 = (s & 1) ? a[7] : a[6];
  ull r4 = (s & 2) ? r1 : r0;
  ull r5 = (s & 2) ? r3 : r2;
  return (s & 4) ? r5 : r4;
}

__device__ __forceinline__ float sel8_f(const float* a, int s) {
  float r0 = (s & 1) ? a[1] : a[0];
  float r1 = (s & 1) ? a[3] : a[2];
  float r2 = (s & 1) ? a[5] : a[4];
  float r3 = (s & 1) ? a[7] : a[6];
  float r4 = (s & 2) ? r1 : r0;
  float r5 = (s & 2) ? r3 : r2;
  return (s & 4) ? r5 : r4;
}

__device__ __forceinline__ ull sel16_u64(const ull* a, int s) {
  ull lo = sel8_u64(a, s);
  ull hi = sel8_u64(a + 8, s);
  return (s & 8) ? hi : lo;
}

__device__ __forceinline__ float sel16_f(const float* a, int s) {
  float lo = sel8_f(a, s);
  float hi = sel8_f(a + 8, s);
  return (s & 8) ? hi : lo;
}

template <int CTRL>
__device__ __forceinline__ float dpp_add(float v) {
  int t = __builtin_amdgcn_update_dpp(0, __float_as_int(v), CTRL, 0xF, 0xF, true);
  return v + __int_as_float(t);
}

// full 64-lane sum: row_ror 1,2,4,8 (VALU pipe) + xor16 (ds_swizzle) + xor32 (shfl)
__device__ __forceinline__ float wave_sum(float v) {
  v = dpp_add<0x121>(v);
  v = dpp_add<0x122>(v);
  v = dpp_add<0x124>(v);
  v = dpp_add<0x128>(v);
  v += __int_as_float(__builtin_amdgcn_ds_swizzle(__float_as_int(v), 0x401F));
  v += __shfl_xor(v, 32);
  return v;
}

__device__ __forceinline__ unsigned short f2bf(float f) {  // fp32 -> bf16 RNE
  unsigned u = __float_as_uint(f);
  return (unsigned short)((u + 0x7FFFu + ((u >> 16) & 1u)) >> 16);
}

// ========================= fused quantize + dequantize =========================
__global__ __launch_bounds__(1024, 4) void rabitq_fused(const float* __restrict__ x,
                                                        const float* __restrict__ Pm,
                                                        float* __restrict__ out) {
  extern __shared__ __align__(16) char smem[];
  float* const Pl = (float*)smem;                    // 64 KiB swizzled fp32 P
  char* const xs = smem + 65536;                     // 16 wave-slots x 4 KiB
  unsigned* const Bp = (unsigned*)(smem + 131072);   // 32 KiB bf16 B-frags

  const int tid = threadIdx.x;
  const int lane = tid & 63;
  const int ww = tid >> 6;
  const int l15 = lane & 15, lg = lane >> 4;

  // ---- prologue 1: stage P into LDS, swizzled (16B blocks, j ^ (row&7)) ----
  {
    const int r = tid >> 3;
    const int q = tid & 7;
#pragma unroll
    for (int c = 0; c < 4; ++c) {
      const int dd = q * 16 + c * 4;
      const int sj = (((dd >> 2) ^ (r & 7)) << 2);
      const float4 v = *(const float4*)(Pm + (size_t)r * 128 + dd);
      *(float4*)(&Pl[r * 128 + sj]) = v;
    }
  }

  // ---- prologue 2: build bf16 B-frags in LDS from global Pm (R5-proven) ----
  // slot s=(ks*512+n*64+l): elem j -> k=ks*32+(l>>4)*8+j, col f=n*16+(l&15)
#pragma unroll
  for (int i = 0; i < 2; ++i) {
    const int s = tid + i * 1024;
    const int ks = s >> 9, n = (s >> 6) & 7, l = s & 63;
    const int kb = ks * 32 + (l >> 4) * 8;
    const int f = n * 16 + (l & 15);
    u32x4v wv;
#pragma unroll
    for (int u = 0; u < 4; ++u) {
      const float p0 = Pm[(size_t)(kb + 2 * u) * 128 + f];
      const float p1 = Pm[(size_t)(kb + 2 * u + 1) * 128 + f];
      wv[u] = (unsigned)f2bf(p0) | ((unsigned)f2bf(p1) << 16);
    }
    *(u32x4v*)(&Bp[s * 4]) = wv;
  }
  __syncthreads();

  const int w = blockIdx.x * 16 + ww;  // global wave id
  float* const out_pack = out + (size_t)NVEC_TOTAL * 128;
  float* const out_norm = out_pack + (size_t)NVEC_TOTAL * 16;
  float* const out_x0   = out_norm + NVEC_TOTAL;

  const int sw1 = lane & 7;
  float* const xb = (float*)(xs + ww * 4096);
  const int lsub = (lane >> 5);
  const int lcol = (lane & 31) * 4;

  // ---- prologue 3: prefetch pass-0 x (per-lane, coalesced) : R8 verbatim ----
  float4 pf0, pf1, pf2, pf3;
  {
    const int vb = w * 32;
    pf0 = *(const float4*)(x + (size_t)(vb + 0 + lsub) * 128 + lcol);
    pf1 = *(const float4*)(x + (size_t)(vb + 2 + lsub) * 128 + lcol);
    pf2 = *(const float4*)(x + (size_t)(vb + 4 + lsub) * 128 + lcol);
    pf3 = *(const float4*)(x + (size_t)(vb + 6 + lsub) * 128 + lcol);
  }

#pragma unroll
  for (int g = 0; g < 2; ++g) {
    ull gL[16], gH[16];   // per-vec 64-bit sign masks (wave-uniform)
    float gSc[16];        // per-vec n16*x016 (wave-uniform)

#pragma unroll
    for (int p = 0; p < 2; ++p) {
      const int t = g * 2 + p;
      const int vbase = w * 32 + t * 8;

      // ---- write staged regs to wave slot : R8 verbatim ----
      {
        char* const dst = (char*)xb + lane * 16;
        *(float4*)(dst + 0)    = pf0;
        *(float4*)(dst + 1024) = pf1;
        *(float4*)(dst + 2048) = pf2;
        *(float4*)(dst + 3072) = pf3;
      }

      // ---- prefetch next pass ----
      if (t + 1 < 4) {
        const int vb = w * 32 + (t + 1) * 8;
        pf0 = *(const float4*)(x + (size_t)(vb + 0 + lsub) * 128 + lcol);
        pf1 = *(const float4*)(x + (size_t)(vb + 2 + lsub) * 128 + lcol);
        pf2 = *(const float4*)(x + (size_t)(vb + 4 + lsub) * 128 + lcol);
        pf3 = *(const float4*)(x + (size_t)(vb + 6 + lsub) * 128 + lcol);
      }

      // ---- x_rot = x @ P^T : R8-verbatim chain (signs proven) ----
      float acc_lo[8], acc_hi[8];
#pragma unroll
      for (int v = 0; v < 8; ++v) { acc_lo[v] = 0.f; acc_hi[v] = 0.f; }

#pragma unroll 2
      for (int j = 0; j < 32; ++j) {
        const int js = ((j ^ sw1) << 2);
        const float4 pl = *(const float4*)(&Pl[lane * 128 + js]);
        const float4 ph = *(const float4*)(&Pl[(lane + 64) * 128 + js]);
#pragma unroll
        for (int v = 0; v < 8; ++v) {
          const float4 xv = *(const float4*)(xb + v * 128 + j * 4);
          float al = acc_lo[v], ah = acc_hi[v];
          al = fmaf(xv.x, pl.x, al); ah = fmaf(xv.x, ph.x, ah);
          al = fmaf(xv.y, pl.y, al); ah = fmaf(xv.y, ph.y, ah);
          al = fmaf(xv.z, pl.z, al); ah = fmaf(xv.z, ph.z, ah);
          al = fmaf(xv.w, pl.w, al); ah = fmaf(xv.w, ph.w, ah);
          acc_lo[v] = al; acc_hi[v] = ah;
        }
      }

      // ---- signs (verbatim), norm/x0 with DPP reduce ----
      ull abl[8], abh[8];
      float n16v[8], x0v[8];
#pragma unroll
      for (int v = 0; v < 8; ++v) {
        abl[v] = __ballot(acc_lo[v] >= 0.0f);
        abh[v] = __ballot(acc_hi[v] >= 0.0f);
        const float a1 = fabsf(acc_lo[v]);
        const float a2 = fabsf(acc_hi[v]);
        const float s1 = wave_sum(a1 + a2);
        const float n2 = wave_sum(fmaf(a1, a1, a2 * a2));
        const float norm = fmaxf(sqrtf(n2), 1e-8f);
        const float n16  = __half2float(__float2half(norm));
        const float x0   = s1 / (128.0f * norm);
        const float x016 = __half2float(__float2half(x0));
        n16v[v] = rfl_f(n16);
        x0v[v]  = rfl_f(x016);
        gL[p * 8 + v] = abl[v];
        gH[p * 8 + v] = abh[v];
        gSc[p * 8 + v] = rfl_f(n16 * x016);
      }

      // ---- packed bytes / norms16 / x016 stores : R8 verbatim ----
      {
        const int s = lane & 7;
        const int jb = lane >> 3;
        const ull el = sel8_u64(abl, s);
        const ull eh = sel8_u64(abh, s);
        const float fl = (float)((unsigned)(el >> (8 * jb)) & 255u);
        const float fh = (float)((unsigned)(eh >> (8 * jb)) & 255u);
        out_pack[(size_t)(vbase + s) * 16 + jb] = fl;
        out_pack[(size_t)(vbase + s) * 16 + 8 + jb] = fh;
        if (lane < 16) {
          const float nsel = sel8_f(n16v, s);
          const float xsel = sel8_f(x0v, s);
          if (lane < 8) out_norm[vbase + s] = nsel;
          else          out_x0[vbase + s] = xsel;
        }
      }
    }

    // ================= dequant group g: vecs gvb..gvb+15 =================
    const int gvb = w * 32 + g * 16;

    // lane's vec = gvb + l15: mask words from wave-uniform ballots (sel16 tree)
    const ull selL = sel16_u64(gL, l15);
    const ull selH = sel16_u64(gH, l15);
    unsigned mw[4];
    mw[0] = (unsigned)selL; mw[1] = (unsigned)(selL >> 32);
    mw[2] = (unsigned)selH; mw[3] = (unsigned)(selH >> 32);

    // A-frags : R2/R5-proven construction
    short8 a8[4];
#pragma unroll
    for (int ks = 0; ks < 4; ++ks) {
      const unsigned nb = (~mw[ks]) >> (lg * 8);
      u32x4v ta;
      ta[0] = 0x3F803F80u | ((nb & 1u) << 15)        | ((nb & 2u) << 30);
      ta[1] = 0x3F803F80u | (((nb >> 2) & 1u) << 15) | (((nb >> 2) & 2u) << 30);
      ta[2] = 0x3F803F80u | (((nb >> 4) & 1u) << 15) | (((nb >> 4) & 2u) << 30);
      ta[3] = 0x3F803F80u | (((nb >> 6) & 1u) << 15) | (((nb >> 6) & 2u) << 30);
      a8[ks] = __builtin_bit_cast(short8, ta);
    }

    // D = S @ bf16(P), B-frags from LDS (R5-proven read path)
    f32x4 dacc[8];
#pragma unroll
    for (int n = 0; n < 8; ++n) { dacc[n][0] = 0.f; dacc[n][1] = 0.f; dacc[n][2] = 0.f; dacc[n][3] = 0.f; }
#pragma unroll
    for (int n = 0; n < 8; ++n) {
#pragma unroll
      for (int ks = 0; ks < 4; ++ks) {
        const short8 b8 = __builtin_bit_cast(short8, *(const u32x4v*)(&Bp[(ks * 512 + n * 64 + lane) * 4]));
        dacc[n] = __builtin_amdgcn_mfma_f32_16x16x32_bf16(a8[ks], b8, dacc[n], 0, 0, 0);
      }
    }

    // scales + stores (C/D: col=l15, row=lg*4+reg — proven)
    float sc[4];
#pragma unroll
    for (int r = 0; r < 4; ++r) sc[r] = sel16_f(gSc, lg * 4 + r);
#pragma unroll
    for (int r = 0; r < 4; ++r) {
      float* op = out + (size_t)(gvb + lg * 4 + r) * 128 + l15;
#pragma unroll
      for (int n = 0; n < 8; ++n) op[n * 16] = sc[r] * dacc[n][r];
    }
  }
}

extern "C" void kernel_launch(void* const* d_in, const int* in_sizes, int n_in,
                              void* d_out, int out_size, void* d_ws, size_t ws_size,
                              hipStream_t stream) {
  const float* x  = (const float*)d_in[0];
  const float* Pm = (const float*)d_in[1];
  float* out = (float*)d_out;
  // 262144 vec / (16 waves * 32 vec) = 512 blocks.
  // Dynamic LDS: 64K P + 64K x-slots + 32K B-frags = 163840 B (160 KiB/CU).
  hipLaunchKernelGGL(rabitq_fused, dim3(512), dim3(1024), 163840, stream, x, Pm, out);
}